// Round 3
// baseline (473.587 us; speedup 1.0000x reference)
//
#include <hip/hip_runtime.h>
#include <hip/hip_bf16.h>

#define D_MODEL 1024
#define NHEAD 16
#define DH 64
#define DFF 4096
#define MAXD 32
#define L_ 2048
#define NROW 4096

typedef __attribute__((ext_vector_type(4))) float floatx4;
typedef __attribute__((ext_vector_type(8))) __bf16 bf16x8;
typedef __attribute__((ext_vector_type(4))) unsigned short ushort4v;

static __device__ inline unsigned short f2bf(float f) {
    __hip_bfloat16 h = __float2bfloat16(f);
    return __builtin_bit_cast(unsigned short, h);
}

static __device__ inline floatx4 mfma16(bf16x8 a, bf16x8 b, floatx4 c) {
    return __builtin_amdgcn_mfma_f32_16x16x32_bf16(a, b, c, 0, 0, 0);
}

static __device__ inline void gload_lds16(const unsigned short* g, unsigned short* l) {
    __builtin_amdgcn_global_load_lds((const __attribute__((address_space(1))) unsigned int*)g,
                                     (__attribute__((address_space(3))) unsigned int*)l,
                                     16, 0, 0);
}

// ---------------- elementwise cast fp32 -> bf16 ----------------
__global__ __launch_bounds__(256) void cast_bf16_kernel(const float* __restrict__ in,
                                                        unsigned short* __restrict__ out, int n4) {
    int i = blockIdx.x * 256 + threadIdx.x;
    if (i < n4) {
        floatx4 v = *(const floatx4*)&in[(size_t)i * 4];
        ushort4v o;
        o.x = f2bf(v[0]); o.y = f2bf(v[1]); o.z = f2bf(v[2]); o.w = f2bf(v[3]);
        *(ushort4v*)&out[(size_t)i * 4] = o;
    }
}

// ---------------- transpose + cast: W fp32 [K][N] -> WT bf16 [N][K] ----------------
__global__ __launch_bounds__(256) void transpose_cast_kernel(const float* __restrict__ W,
                                                             unsigned short* __restrict__ WT,
                                                             int K, int N) {
    __shared__ float tile[32][33];
    int k0 = blockIdx.y * 32, n0 = blockIdx.x * 32;
    for (int i = threadIdx.x; i < 1024; i += 256) {
        int r = i >> 5, c = i & 31;
        tile[r][c] = W[(size_t)(k0 + r) * N + n0 + c];
    }
    __syncthreads();
    for (int i = threadIdx.x; i < 1024; i += 256) {
        int r = i >> 5, c = i & 31;
        WT[(size_t)(n0 + r) * K + k0 + c] = f2bf(tile[c][r]);
    }
}

// ---------------- pack qkv bias ----------------
__global__ __launch_bounds__(256) void pack_bias_kernel(const float* __restrict__ bq,
                                                        const float* __restrict__ bk,
                                                        const float* __restrict__ bv,
                                                        float* __restrict__ out) {
    int i = blockIdx.x * 256 + threadIdx.x;
    if (i < 3072) out[i] = (i < 1024) ? bq[i] : ((i < 2048) ? bk[i - 1024] : bv[i - 2048]);
}

// ---------------- GEMM: C[M][N] = A[M][K] @ BT[N][K]^T + bias ----------------
// m97 structure: 128 x (NF*32) tile, 4 waves, BK=32, global_load_lds width-16 staging.
template <int NF, bool OUTBF16, bool RELU>
__global__ __launch_bounds__(256) void gemm_kernel(const unsigned short* __restrict__ A,
                                                   const unsigned short* __restrict__ BT,
                                                   const float* __restrict__ bias,
                                                   void* __restrict__ Cout,
                                                   int M, int N, int K) {
    constexpr int BN = NF * 32;
    __shared__ unsigned short Asm[128][32];
    __shared__ unsigned short Bsm[BN][32];
    int t = threadIdx.x;
    int lane = t & 63, w = t >> 6;
    int wm = w >> 1, wn = w & 1;
    int lr = lane & 15, hg = lane >> 4;
    int m0 = blockIdx.y * 128, n0 = blockIdx.x * BN;

    floatx4 acc[4][NF];
#pragma unroll
    for (int i = 0; i < 4; i++)
#pragma unroll
        for (int j = 0; j < NF; j++) acc[i][j] = (floatx4)0.0f;

    int r0 = t >> 2, c0 = (t & 3) * 8;

    for (int k0 = 0; k0 < K; k0 += 32) {
        __syncthreads();
        gload_lds16(&A[(size_t)(m0 + r0) * K + k0 + c0], &Asm[r0][c0]);
        gload_lds16(&A[(size_t)(m0 + r0 + 64) * K + k0 + c0], &Asm[r0 + 64][c0]);
        gload_lds16(&BT[(size_t)(n0 + r0) * K + k0 + c0], &Bsm[r0][c0]);
        if (NF == 4)
            gload_lds16(&BT[(size_t)(n0 + r0 + 64) * K + k0 + c0], &Bsm[r0 + 64][c0]);
        __syncthreads();
        bf16x8 af[4], bfg[NF];
#pragma unroll
        for (int mf = 0; mf < 4; mf++) af[mf] = *(const bf16x8*)&Asm[wm * 64 + mf * 16 + lr][hg * 8];
#pragma unroll
        for (int nf = 0; nf < NF; nf++)
            bfg[nf] = *(const bf16x8*)&Bsm[wn * NF * 16 + nf * 16 + lr][hg * 8];
#pragma unroll
        for (int mf = 0; mf < 4; mf++)
#pragma unroll
            for (int nf = 0; nf < NF; nf++) acc[mf][nf] = mfma16(af[mf], bfg[nf], acc[mf][nf]);
    }

#pragma unroll
    for (int mf = 0; mf < 4; mf++)
#pragma unroll
        for (int nf = 0; nf < NF; nf++) {
            int col = n0 + wn * NF * 16 + nf * 16 + lr;
            float bv = bias[col];
#pragma unroll
            for (int r = 0; r < 4; r++) {
                int row = m0 + wm * 64 + mf * 16 + hg * 4 + r;
                float v = acc[mf][nf][r] + bv;
                if (RELU) v = v > 0.f ? v : 0.f;
                if (OUTBF16)
                    ((unsigned short*)Cout)[(size_t)row * N + col] = f2bf(v);
                else
                    ((float*)Cout)[(size_t)row * N + col] = v;
            }
        }
}

// ---------------- fused attention with RPE bias ----------------
// 512 blocks x 512 threads. 8 waves x 16 q-rows = 128 q rows/block. KV tile = 64.
// Static K double-buffer (no dynamic indexing), async-split staging (T14),
// per-lane partial l-sum, defer-max (T13), setprio around MFMA (T5).
__global__ __launch_bounds__(512, 4) void attn_kernel(const unsigned short* __restrict__ qkv, // [4096][3072]
                                                      const float* __restrict__ rpe,          // [65][16]
                                                      unsigned short* __restrict__ ctx) {     // [4096][1024]
    __shared__ unsigned short QP[128][68];     // Q staging, then per-wave-private P tiles
    __shared__ unsigned short K0s[64][68];
    __shared__ unsigned short K1s[64][68];
    __shared__ unsigned short Vt[64][68];      // transposed V: [d][key]
    __shared__ float rpl[65];

    int t = threadIdx.x;
    int lane = t & 63, w = t >> 6;
    int lr = lane & 15, hg = lane >> 4;

    int blk = blockIdx.x;
    int qb = blk & 15;
    int h = (blk >> 4) & 15;
    int b = blk >> 8;
    int q0 = qb * 128;
    size_t rowbase = (size_t)b * L_ * 3072;

    if (t < 65) rpl[t] = rpe[t * NHEAD + h];

    // stage Q: 128 rows x 64 cols = 1024 16B chunks, 2 per thread
    {
        int idx = t, r = idx >> 3, ch = idx & 7;
        *(int4*)&QP[r][ch * 8] = *(const int4*)&qkv[rowbase + (size_t)(q0 + r) * 3072 + h * 64 + ch * 8];
        idx = t + 512; r = idx >> 3; ch = idx & 7;
        *(int4*)&QP[r][ch * 8] = *(const int4*)&qkv[rowbase + (size_t)(q0 + r) * 3072 + h * 64 + ch * 8];
    }
    // stage K tile 0
    int kr = t >> 3, kch = t & 7;
    *(int4*)&K0s[kr][kch * 8] = *(const int4*)&qkv[rowbase + (size_t)kr * 3072 + 1024 + h * 64 + kch * 8];
    __syncthreads();

    bf16x8 qf[2];
    qf[0] = *(const bf16x8*)&QP[w * 16 + lr][hg * 8];
    qf[1] = *(const bf16x8*)&QP[w * 16 + lr][32 + hg * 8];
    float rpl0 = rpl[0], rpl64 = rpl[64];

    floatx4 o[4];
#pragma unroll
    for (int nf = 0; nf < 4; nf++) o[nf] = (floatx4)0.f;
    float mst[4], lst[4];
#pragma unroll
    for (int r = 0; r < 4; r++) { mst[r] = -1e30f; lst[r] = 0.f; }

    const float scale = 0.125f;

    auto body = [&](int kt, unsigned short (*Kc)[68], unsigned short (*Kn)[68]) {
        int key0 = kt * 64;
        // issue global loads early; LDS writes deferred past softmax (T14)
        union { int4 v; unsigned short u[8]; } tvV, tvK;
        tvV.v = *(const int4*)&qkv[rowbase + (size_t)(key0 + kr) * 3072 + 2048 + h * 64 + kch * 8];
        bool more = (kt + 1 < L_ / 64);
        if (more)
            tvK.v = *(const int4*)&qkv[rowbase + (size_t)(key0 + 64 + kr) * 3072 + 1024 + h * 64 + kch * 8];

        // S = Q K^T
        floatx4 s[4];
        __builtin_amdgcn_s_setprio(1);
#pragma unroll
        for (int nf = 0; nf < 4; nf++) {
            floatx4 a = (floatx4)0.f;
            a = mfma16(qf[0], *(const bf16x8*)&Kc[nf * 16 + lr][hg * 8], a);
            a = mfma16(qf[1], *(const bf16x8*)&Kc[nf * 16 + lr][32 + hg * 8], a);
            s[nf] = a;
        }
        __builtin_amdgcn_s_setprio(0);

        // constant-bias fast path when tile fully outside the +/-32 band
        bool rightC = (key0 > q0 + 159);
        bool leftC = (key0 + 95 < q0);
        bool cc = leftC || rightC;
        float cb = rightC ? rpl64 : rpl0;

        // online softmax; lst kept per-lane partial (corr is row-uniform)
#pragma unroll
        for (int r = 0; r < 4; r++) {
            float sv[4];
            float mx = -1e30f;
            if (cc) {
#pragma unroll
                for (int nf = 0; nf < 4; nf++) {
                    float v = s[nf][r] * scale + cb;
                    sv[nf] = v;
                    mx = fmaxf(mx, v);
                }
            } else {
                int qi = q0 + w * 16 + hg * 4 + r;
#pragma unroll
                for (int nf = 0; nf < 4; nf++) {
                    int rel = key0 + nf * 16 + lr - qi;
                    rel = rel < -MAXD ? -MAXD : (rel > MAXD ? MAXD : rel);
                    float v = s[nf][r] * scale + rpl[rel + MAXD];
                    sv[nf] = v;
                    mx = fmaxf(mx, v);
                }
            }
#pragma unroll
            for (int d = 1; d < 16; d <<= 1) mx = fmaxf(mx, __shfl_xor(mx, d, 64));
            if (!__all(mx - mst[r] <= 8.f)) {     // defer-max: skip rescale when growth small
                float newm = fmaxf(mst[r], mx);
                float corr = __expf(mst[r] - newm);
                lst[r] *= corr;
#pragma unroll
                for (int nf = 0; nf < 4; nf++) o[nf][r] *= corr;
                mst[r] = newm;
            }
            float ps = 0.f;
#pragma unroll
            for (int nf = 0; nf < 4; nf++) {
                float p = __expf(sv[nf] - mst[r]);
                ps += p;
                QP[w * 16 + hg * 4 + r][nf * 16 + lr] = f2bf(p);
            }
            lst[r] += ps;
        }

        // deferred staging writes (vmcnt drains here, hidden under QK^T+softmax)
        if (more) *(int4*)&Kn[kr][kch * 8] = tvK.v;
#pragma unroll
        for (int j = 0; j < 8; j++) {
            int e = (kch + j) & 7;
            Vt[kch * 8 + e][kr] = tvV.u[e];
        }
        __syncthreads();   // B_mid: Vt + K-next visible

        // O += P @ V   (P rows are wave-private in QP)
        __builtin_amdgcn_s_setprio(1);
        bf16x8 pf0 = *(const bf16x8*)&QP[w * 16 + lr][hg * 8];
        bf16x8 pf1 = *(const bf16x8*)&QP[w * 16 + lr][32 + hg * 8];
#pragma unroll
        for (int nf = 0; nf < 4; nf++) {
            bf16x8 vf0 = *(const bf16x8*)&Vt[nf * 16 + lr][hg * 8];
            bf16x8 vf1 = *(const bf16x8*)&Vt[nf * 16 + lr][32 + hg * 8];
            o[nf] = mfma16(pf0, vf0, o[nf]);
            o[nf] = mfma16(pf1, vf1, o[nf]);
        }
        __builtin_amdgcn_s_setprio(0);
        __syncthreads();   // B_end: PV reads of Vt done before next overwrite
    };

    for (int kt = 0; kt < L_ / 64; kt += 2) {
        body(kt, K0s, K1s);
        body(kt + 1, K1s, K0s);
    }

    // final 16-lane reduce of per-lane partial sums, normalize, write ctx
#pragma unroll
    for (int r = 0; r < 4; r++) {
        float rs = lst[r];
#pragma unroll
        for (int d = 1; d < 16; d <<= 1) rs += __shfl_xor(rs, d, 64);
        float inv = 1.f / rs;
        int row = b * L_ + q0 + w * 16 + hg * 4 + r;
#pragma unroll
        for (int nf = 0; nf < 4; nf++)
            ctx[(size_t)row * 1024 + h * 64 + nf * 16 + lr] = f2bf(o[nf][r] * inv);
    }
}

// ---------------- fused residual + layernorm ----------------
template <bool WBF>
__global__ __launch_bounds__(256) void resln_kernel(const float* __restrict__ ra,
                                                    const float* __restrict__ rb,
                                                    const float* __restrict__ g,
                                                    const float* __restrict__ be,
                                                    float* __restrict__ outf,
                                                    unsigned short* __restrict__ outb) {
    __shared__ float red[4];
    __shared__ float red2[4];
    int row = blockIdx.x;
    int t = threadIdx.x;
    int w = t >> 6, lane = t & 63;
    size_t base = (size_t)row * 1024 + t * 4;
    floatx4 a = *(const floatx4*)&ra[base];
    floatx4 b = *(const floatx4*)&rb[base];
    floatx4 y = a + b;
    float s = y[0] + y[1] + y[2] + y[3];
#pragma unroll
    for (int d = 1; d < 64; d <<= 1) s += __shfl_xor(s, d, 64);
    if (lane == 0) red[w] = s;
    __syncthreads();
    float mu = (red[0] + red[1] + red[2] + red[3]) * (1.f / 1024.f);
    floatx4 d4 = y - mu;
    float sq = d4[0] * d4[0] + d4[1] * d4[1] + d4[2] * d4[2] + d4[3] * d4[3];
#pragma unroll
    for (int d = 1; d < 64; d <<= 1) sq += __shfl_xor(sq, d, 64);
    if (lane == 0) red2[w] = sq;
    __syncthreads();
    float var = (red2[0] + red2[1] + red2[2] + red2[3]) * (1.f / 1024.f);
    float rstd = rsqrtf(var + 1e-5f);
    floatx4 gg = *(const floatx4*)&g[t * 4];
    floatx4 bb = *(const floatx4*)&be[t * 4];
    floatx4 outv;
#pragma unroll
    for (int i = 0; i < 4; i++) outv[i] = d4[i] * rstd * gg[i] + bb[i];
    *(floatx4*)&outf[base] = outv;
    if (WBF) {
        ushort4v ov;
        ov.x = f2bf(outv[0]); ov.y = f2bf(outv[1]); ov.z = f2bf(outv[2]); ov.w = f2bf(outv[3]);
        *(ushort4v*)&outb[base] = ov;
    }
}

extern "C" void kernel_launch(void* const* d_in, const int* in_sizes, int n_in,
                              void* d_out, int out_size, void* d_ws, size_t ws_size,
                              hipStream_t stream) {
    const float* src = (const float*)d_in[0];
    const float* Wq = (const float*)d_in[1];
    const float* Wk = (const float*)d_in[2];
    const float* Wv = (const float*)d_in[3];
    const float* bq = (const float*)d_in[4];
    const float* bk = (const float*)d_in[5];
    const float* bv = (const float*)d_in[6];
    const float* Wo = (const float*)d_in[7];
    const float* bo = (const float*)d_in[8];
    const float* rpe = (const float*)d_in[9];
    const float* W1 = (const float*)d_in[10];
    const float* b1 = (const float*)d_in[11];
    const float* W2 = (const float*)d_in[12];
    const float* b2 = (const float*)d_in[13];
    const float* ln1g = (const float*)d_in[14];
    const float* ln1b = (const float*)d_in[15];
    const float* ln2g = (const float*)d_in[16];
    const float* ln2b = (const float*)d_in[17];
    float* out = (float*)d_out;
    char* ws = (char*)d_ws;

    const size_t o_srcb = 0;                       // 8 MB   bf16 src; later reused as xb
    const size_t o_wtqkv = o_srcb + 8388608;       // 6 MB
    const size_t o_wto = o_wtqkv + 6291456;        // 2 MB
    const size_t o_wt1 = o_wto + 2097152;          // 8 MB
    const size_t o_wt2 = o_wt1 + 8388608;          // 8 MB
    const size_t o_bqkv = o_wt2 + 8388608;         // 12 KB
    const size_t o_qkv = o_bqkv + 12288;           // 24 MB  qkv bf16; later reused as attnout/ff fp32
    const size_t o_ctxb = o_qkv + 25165824;        // 8 MB
    const size_t o_x = o_ctxb + 8388608;           // 16 MB
    const size_t o_hb = o_x + 16777216;            // 32 MB

    unsigned short* srcb = (unsigned short*)(ws + o_srcb);
    unsigned short* wtqkv = (unsigned short*)(ws + o_wtqkv);
    unsigned short* wto = (unsigned short*)(ws + o_wto);
    unsigned short* wt1 = (unsigned short*)(ws + o_wt1);
    unsigned short* wt2 = (unsigned short*)(ws + o_wt2);
    float* bqkv = (float*)(ws + o_bqkv);
    unsigned short* qkvb = (unsigned short*)(ws + o_qkv);
    unsigned short* ctxb = (unsigned short*)(ws + o_ctxb);
    float* x = (float*)(ws + o_x);
    unsigned short* hb = (unsigned short*)(ws + o_hb);
    float* attnout = (float*)(ws + o_qkv);
    float* ff = (float*)(ws + o_qkv);
    unsigned short* xb = (unsigned short*)(ws + o_srcb);

    cast_bf16_kernel<<<4096, 256, 0, stream>>>(src, srcb, 1048576);
    transpose_cast_kernel<<<dim3(32, 32), 256, 0, stream>>>(Wq, wtqkv, 1024, 1024);
    transpose_cast_kernel<<<dim3(32, 32), 256, 0, stream>>>(Wk, wtqkv + 1024 * 1024, 1024, 1024);
    transpose_cast_kernel<<<dim3(32, 32), 256, 0, stream>>>(Wv, wtqkv + 2 * 1024 * 1024, 1024, 1024);
    transpose_cast_kernel<<<dim3(32, 32), 256, 0, stream>>>(Wo, wto, 1024, 1024);
    transpose_cast_kernel<<<dim3(128, 32), 256, 0, stream>>>(W1, wt1, 1024, 4096);
    transpose_cast_kernel<<<dim3(32, 128), 256, 0, stream>>>(W2, wt2, 4096, 1024);
    pack_bias_kernel<<<12, 256, 0, stream>>>(bq, bk, bv, bqkv);

    gemm_kernel<4, true, false><<<dim3(24, 32), 256, 0, stream>>>(srcb, wtqkv, bqkv, qkvb, NROW, 3072, 1024);
    attn_kernel<<<512, 512, 0, stream>>>(qkvb, rpe, ctxb);
    gemm_kernel<2, false, false><<<dim3(16, 32), 256, 0, stream>>>(ctxb, wto, bo, attnout, NROW, 1024, 1024);
    resln_kernel<true><<<4096, 256, 0, stream>>>(src, attnout, ln1g, ln1b, x, xb);
    gemm_kernel<4, true, true><<<dim3(32, 32), 256, 0, stream>>>(xb, wt1, b1, hb, NROW, 4096, 1024);
    gemm_kernel<2, false, false><<<dim3(16, 32), 256, 0, stream>>>(hb, wt2, b2, ff, NROW, 1024, 4096);
    resln_kernel<false><<<4096, 256, 0, stream>>>(x, ff, ln2g, ln2b, out, nullptr);
}

// Round 4
// 463.089 us; speedup vs baseline: 1.0227x; 1.0227x over previous
//
#include <hip/hip_runtime.h>
#include <hip/hip_bf16.h>

#define D_MODEL 1024
#define NHEAD 16
#define DH 64
#define DFF 4096
#define MAXD 32
#define L_ 2048
#define NROW 4096

typedef __attribute__((ext_vector_type(4))) float floatx4;
typedef __attribute__((ext_vector_type(8))) __bf16 bf16x8;
typedef __attribute__((ext_vector_type(4))) unsigned short ushort4v;

static __device__ inline unsigned short f2bf(float f) {
    __hip_bfloat16 h = __float2bfloat16(f);
    return __builtin_bit_cast(unsigned short, h);
}

static __device__ inline floatx4 mfma16(bf16x8 a, bf16x8 b, floatx4 c) {
    return __builtin_amdgcn_mfma_f32_16x16x32_bf16(a, b, c, 0, 0, 0);
}

static __device__ inline void gload_lds16(const unsigned short* g, unsigned short* l) {
    __builtin_amdgcn_global_load_lds((const __attribute__((address_space(1))) unsigned int*)g,
                                     (__attribute__((address_space(3))) unsigned int*)l,
                                     16, 0, 0);
}

// ---------------- elementwise cast fp32 -> bf16 ----------------
__global__ __launch_bounds__(256) void cast_bf16_kernel(const float* __restrict__ in,
                                                        unsigned short* __restrict__ out, int n4) {
    int i = blockIdx.x * 256 + threadIdx.x;
    if (i < n4) {
        floatx4 v = *(const floatx4*)&in[(size_t)i * 4];
        ushort4v o;
        o.x = f2bf(v[0]); o.y = f2bf(v[1]); o.z = f2bf(v[2]); o.w = f2bf(v[3]);
        *(ushort4v*)&out[(size_t)i * 4] = o;
    }
}

// ---------------- transpose + cast: W fp32 [K][N] -> WT bf16 [N][K] ----------------
__global__ __launch_bounds__(256) void transpose_cast_kernel(const float* __restrict__ W,
                                                             unsigned short* __restrict__ WT,
                                                             int K, int N) {
    __shared__ float tile[32][33];
    int k0 = blockIdx.y * 32, n0 = blockIdx.x * 32;
    for (int i = threadIdx.x; i < 1024; i += 256) {
        int r = i >> 5, c = i & 31;
        tile[r][c] = W[(size_t)(k0 + r) * N + n0 + c];
    }
    __syncthreads();
    for (int i = threadIdx.x; i < 1024; i += 256) {
        int r = i >> 5, c = i & 31;
        WT[(size_t)(n0 + r) * K + k0 + c] = f2bf(tile[c][r]);
    }
}

// ---------------- pack qkv bias ----------------
__global__ __launch_bounds__(256) void pack_bias_kernel(const float* __restrict__ bq,
                                                        const float* __restrict__ bk,
                                                        const float* __restrict__ bv,
                                                        float* __restrict__ out) {
    int i = blockIdx.x * 256 + threadIdx.x;
    if (i < 3072) out[i] = (i < 1024) ? bq[i] : ((i < 2048) ? bk[i - 1024] : bv[i - 2048]);
}

// ---------------- GEMM: C[M][N] = A[M][K] @ BT[N][K]^T + bias ----------------
template <int NF, bool OUTBF16, bool RELU>
__global__ __launch_bounds__(256) void gemm_kernel(const unsigned short* __restrict__ A,
                                                   const unsigned short* __restrict__ BT,
                                                   const float* __restrict__ bias,
                                                   void* __restrict__ Cout,
                                                   int M, int N, int K) {
    constexpr int BN = NF * 32;
    __shared__ unsigned short Asm[128][32];
    __shared__ unsigned short Bsm[BN][32];
    int t = threadIdx.x;
    int lane = t & 63, w = t >> 6;
    int wm = w >> 1, wn = w & 1;
    int lr = lane & 15, hg = lane >> 4;
    int m0 = blockIdx.y * 128, n0 = blockIdx.x * BN;

    floatx4 acc[4][NF];
#pragma unroll
    for (int i = 0; i < 4; i++)
#pragma unroll
        for (int j = 0; j < NF; j++) acc[i][j] = (floatx4)0.0f;

    int r0 = t >> 2, c0 = (t & 3) * 8;

    for (int k0 = 0; k0 < K; k0 += 32) {
        __syncthreads();
        gload_lds16(&A[(size_t)(m0 + r0) * K + k0 + c0], &Asm[r0][c0]);
        gload_lds16(&A[(size_t)(m0 + r0 + 64) * K + k0 + c0], &Asm[r0 + 64][c0]);
        gload_lds16(&BT[(size_t)(n0 + r0) * K + k0 + c0], &Bsm[r0][c0]);
        if (NF == 4)
            gload_lds16(&BT[(size_t)(n0 + r0 + 64) * K + k0 + c0], &Bsm[r0 + 64][c0]);
        __syncthreads();
        bf16x8 af[4], bfg[NF];
#pragma unroll
        for (int mf = 0; mf < 4; mf++) af[mf] = *(const bf16x8*)&Asm[wm * 64 + mf * 16 + lr][hg * 8];
#pragma unroll
        for (int nf = 0; nf < NF; nf++)
            bfg[nf] = *(const bf16x8*)&Bsm[wn * NF * 16 + nf * 16 + lr][hg * 8];
#pragma unroll
        for (int mf = 0; mf < 4; mf++)
#pragma unroll
            for (int nf = 0; nf < NF; nf++) acc[mf][nf] = mfma16(af[mf], bfg[nf], acc[mf][nf]);
    }

#pragma unroll
    for (int mf = 0; mf < 4; mf++)
#pragma unroll
        for (int nf = 0; nf < NF; nf++) {
            int col = n0 + wn * NF * 16 + nf * 16 + lr;
            float bv = bias[col];
#pragma unroll
            for (int r = 0; r < 4; r++) {
                int row = m0 + wm * 64 + mf * 16 + hg * 4 + r;
                float v = acc[mf][nf][r] + bv;
                if (RELU) v = v > 0.f ? v : 0.f;
                if (OUTBF16)
                    ((unsigned short*)Cout)[(size_t)row * N + col] = f2bf(v);
                else
                    ((float*)Cout)[(size_t)row * N + col] = v;
            }
        }
}

// ---------------- fused attention with RPE bias ----------------
// 1024 blocks x 256 threads. 4 waves x 16 q-rows = 64 q rows/block. KV tile = 64.
// Round-2 math exactly; static K dbuf (macro, no lambda), deferred LDS writes (T14).
union U16x8 { int4 v; unsigned short u[8]; };

#define ATTN_STEP(KT, Kc, Kn, MORE)                                                                \
    {                                                                                              \
        const int key0 = (KT) * 64;                                                                \
        U16x8 tv0, tv1;                                                                            \
        int4 tk0 = {0, 0, 0, 0}, tk1 = {0, 0, 0, 0};                                               \
        tv0.v = *(const int4*)&qkv[rowbase + (size_t)(key0 + r0) * 3072 + 2048 + hcol + c0];       \
        tv1.v = *(const int4*)&qkv[rowbase + (size_t)(key0 + r0 + 32) * 3072 + 2048 + hcol + c0];  \
        if (MORE) {                                                                                \
            tk0 = *(const int4*)&qkv[rowbase + (size_t)(key0 + 64 + r0) * 3072 + 1024 + hcol + c0];\
            tk1 = *(const int4*)&qkv[rowbase + (size_t)(key0 + 96 + r0) * 3072 + 1024 + hcol + c0];\
        }                                                                                          \
        floatx4 s[4];                                                                              \
        _Pragma("unroll")                                                                          \
        for (int nf = 0; nf < 4; nf++) {                                                           \
            floatx4 a = (floatx4)0.f;                                                              \
            a = mfma16(qf0, *(const bf16x8*)&Kc[nf * 16 + lr][hg * 8], a);                         \
            a = mfma16(qf1, *(const bf16x8*)&Kc[nf * 16 + lr][32 + hg * 8], a);                    \
            s[nf] = a;                                                                             \
        }                                                                                          \
        bool rightC = (key0 > q0 + 95);                                                            \
        bool leftC = (key0 + 95 < q0);                                                             \
        bool ccp = leftC || rightC;                                                                \
        float cbv = rightC ? rpl64 : rpl0;                                                         \
        _Pragma("unroll")                                                                          \
        for (int r = 0; r < 4; r++) {                                                              \
            float sv[4];                                                                           \
            float mx = -1e30f;                                                                     \
            if (ccp) {                                                                             \
                _Pragma("unroll")                                                                  \
                for (int nf = 0; nf < 4; nf++) {                                                   \
                    float v = s[nf][r] * scale + cbv;                                              \
                    sv[nf] = v;                                                                    \
                    mx = fmaxf(mx, v);                                                             \
                }                                                                                  \
            } else {                                                                               \
                int qi = q0 + w * 16 + hg * 4 + r;                                                 \
                _Pragma("unroll")                                                                  \
                for (int nf = 0; nf < 4; nf++) {                                                   \
                    int rel = key0 + nf * 16 + lr - qi;                                            \
                    rel = rel < -MAXD ? -MAXD : (rel > MAXD ? MAXD : rel);                         \
                    float v = s[nf][r] * scale + rpl[rel + MAXD];                                  \
                    sv[nf] = v;                                                                    \
                    mx = fmaxf(mx, v);                                                             \
                }                                                                                  \
            }                                                                                      \
            _Pragma("unroll")                                                                      \
            for (int d = 1; d < 16; d <<= 1) mx = fmaxf(mx, __shfl_xor(mx, d, 64));                \
            float newm = fmaxf(mst[r], mx);                                                        \
            float corr = __expf(mst[r] - newm);                                                    \
            float rs = 0.f;                                                                        \
            _Pragma("unroll")                                                                      \
            for (int nf = 0; nf < 4; nf++) {                                                       \
                float p = __expf(sv[nf] - newm);                                                   \
                rs += p;                                                                           \
                QP[w * 16 + hg * 4 + r][nf * 16 + lr] = f2bf(p);                                   \
            }                                                                                      \
            _Pragma("unroll")                                                                      \
            for (int d = 1; d < 16; d <<= 1) rs += __shfl_xor(rs, d, 64);                          \
            lst[r] = lst[r] * corr + rs;                                                           \
            mst[r] = newm;                                                                         \
            _Pragma("unroll")                                                                      \
            for (int nf = 0; nf < 4; nf++) o[nf][r] *= corr;                                       \
        }                                                                                          \
        if (MORE) {                                                                                \
            *(int4*)&Kn[r0][c0] = tk0;                                                             \
            *(int4*)&Kn[r0 + 32][c0] = tk1;                                                        \
        }                                                                                          \
        _Pragma("unroll")                                                                          \
        for (int j = 0; j < 8; j++) {                                                              \
            int e = (kch + j) & 7;                                                                 \
            Vt[kch * 8 + e][r0] = tv0.u[e];                                                        \
            Vt[kch * 8 + e][r0 + 32] = tv1.u[e];                                                   \
        }                                                                                          \
        __syncthreads();                                                                           \
        bf16x8 pf0 = *(const bf16x8*)&QP[w * 16 + lr][hg * 8];                                     \
        bf16x8 pf1 = *(const bf16x8*)&QP[w * 16 + lr][32 + hg * 8];                                \
        _Pragma("unroll")                                                                          \
        for (int nf = 0; nf < 4; nf++) {                                                           \
            bf16x8 vf0 = *(const bf16x8*)&Vt[nf * 16 + lr][hg * 8];                                \
            bf16x8 vf1 = *(const bf16x8*)&Vt[nf * 16 + lr][32 + hg * 8];                           \
            o[nf] = mfma16(pf0, vf0, o[nf]);                                                       \
            o[nf] = mfma16(pf1, vf1, o[nf]);                                                       \
        }                                                                                          \
        __syncthreads();                                                                           \
    }

__global__ __launch_bounds__(256, 4) void attn_kernel(const unsigned short* __restrict__ qkv, // [4096][3072]
                                                      const float* __restrict__ rpe,          // [65][16]
                                                      unsigned short* __restrict__ ctx) {     // [4096][1024]
    __shared__ unsigned short QP[64][68];      // Q staging, then per-wave-private P tiles
    __shared__ unsigned short K0s[64][68];
    __shared__ unsigned short K1s[64][68];
    __shared__ unsigned short Vt[64][68];      // transposed V: [d][key]
    __shared__ float rpl[65];

    int t = threadIdx.x;
    int lane = t & 63, w = t >> 6;
    int lr = lane & 15, hg = lane >> 4;

    int blk = blockIdx.x;
    int qb = blk & 31;
    int h = (blk >> 5) & 15;
    int b = blk >> 9;
    int q0 = qb * 64;
    int hcol = h * 64;
    size_t rowbase = (size_t)b * L_ * 3072;

    int r0 = t >> 3, c0 = (t & 7) * 8, kch = t & 7;

    if (t < 65) rpl[t] = rpe[t * NHEAD + h];

    // stage Q (64 rows x 64 cols) and K tile 0
    *(int4*)&QP[r0][c0] = *(const int4*)&qkv[rowbase + (size_t)(q0 + r0) * 3072 + hcol + c0];
    *(int4*)&QP[r0 + 32][c0] = *(const int4*)&qkv[rowbase + (size_t)(q0 + r0 + 32) * 3072 + hcol + c0];
    *(int4*)&K0s[r0][c0] = *(const int4*)&qkv[rowbase + (size_t)r0 * 3072 + 1024 + hcol + c0];
    *(int4*)&K0s[r0 + 32][c0] = *(const int4*)&qkv[rowbase + (size_t)(r0 + 32) * 3072 + 1024 + hcol + c0];
    __syncthreads();

    bf16x8 qf0 = *(const bf16x8*)&QP[w * 16 + lr][hg * 8];
    bf16x8 qf1 = *(const bf16x8*)&QP[w * 16 + lr][32 + hg * 8];
    float rpl0 = rpl[0], rpl64 = rpl[64];

    floatx4 o[4];
#pragma unroll
    for (int nf = 0; nf < 4; nf++) o[nf] = (floatx4)0.f;
    float mst[4], lst[4];
#pragma unroll
    for (int r = 0; r < 4; r++) { mst[r] = -1e30f; lst[r] = 0.f; }

    const float scale = 0.125f;

    for (int kt = 0; kt < L_ / 64; kt += 2) {
        ATTN_STEP(kt, K0s, K1s, true);
        ATTN_STEP(kt + 1, K1s, K0s, (kt + 2 < L_ / 64));
    }

    // normalize + write ctx (bf16)
#pragma unroll
    for (int r = 0; r < 4; r++) {
        float inv = 1.f / lst[r];
        int row = b * L_ + q0 + w * 16 + hg * 4 + r;
#pragma unroll
        for (int nf = 0; nf < 4; nf++)
            ctx[(size_t)row * 1024 + hcol + nf * 16 + lr] = f2bf(o[nf][r] * inv);
    }
}

// ---------------- fused residual + layernorm ----------------
template <bool WBF>
__global__ __launch_bounds__(256) void resln_kernel(const float* __restrict__ ra,
                                                    const float* __restrict__ rb,
                                                    const float* __restrict__ g,
                                                    const float* __restrict__ be,
                                                    float* __restrict__ outf,
                                                    unsigned short* __restrict__ outb) {
    __shared__ float red[4];
    __shared__ float red2[4];
    int row = blockIdx.x;
    int t = threadIdx.x;
    int w = t >> 6, lane = t & 63;
    size_t base = (size_t)row * 1024 + t * 4;
    floatx4 a = *(const floatx4*)&ra[base];
    floatx4 b = *(const floatx4*)&rb[base];
    floatx4 y = a + b;
    float s = y[0] + y[1] + y[2] + y[3];
#pragma unroll
    for (int d = 1; d < 64; d <<= 1) s += __shfl_xor(s, d, 64);
    if (lane == 0) red[w] = s;
    __syncthreads();
    float mu = (red[0] + red[1] + red[2] + red[3]) * (1.f / 1024.f);
    floatx4 d4 = y - mu;
    float sq = d4[0] * d4[0] + d4[1] * d4[1] + d4[2] * d4[2] + d4[3] * d4[3];
#pragma unroll
    for (int d = 1; d < 64; d <<= 1) sq += __shfl_xor(sq, d, 64);
    if (lane == 0) red2[w] = sq;
    __syncthreads();
    float var = (red2[0] + red2[1] + red2[2] + red2[3]) * (1.f / 1024.f);
    float rstd = rsqrtf(var + 1e-5f);
    floatx4 gg = *(const floatx4*)&g[t * 4];
    floatx4 bb = *(const floatx4*)&be[t * 4];
    floatx4 outv;
#pragma unroll
    for (int i = 0; i < 4; i++) outv[i] = d4[i] * rstd * gg[i] + bb[i];
    *(floatx4*)&outf[base] = outv;
    if (WBF) {
        ushort4v ov;
        ov.x = f2bf(outv[0]); ov.y = f2bf(outv[1]); ov.z = f2bf(outv[2]); ov.w = f2bf(outv[3]);
        *(ushort4v*)&outb[base] = ov;
    }
}

extern "C" void kernel_launch(void* const* d_in, const int* in_sizes, int n_in,
                              void* d_out, int out_size, void* d_ws, size_t ws_size,
                              hipStream_t stream) {
    const float* src = (const float*)d_in[0];
    const float* Wq = (const float*)d_in[1];
    const float* Wk = (const float*)d_in[2];
    const float* Wv = (const float*)d_in[3];
    const float* bq = (const float*)d_in[4];
    const float* bk = (const float*)d_in[5];
    const float* bv = (const float*)d_in[6];
    const float* Wo = (const float*)d_in[7];
    const float* bo = (const float*)d_in[8];
    const float* rpe = (const float*)d_in[9];
    const float* W1 = (const float*)d_in[10];
    const float* b1 = (const float*)d_in[11];
    const float* W2 = (const float*)d_in[12];
    const float* b2 = (const float*)d_in[13];
    const float* ln1g = (const float*)d_in[14];
    const float* ln1b = (const float*)d_in[15];
    const float* ln2g = (const float*)d_in[16];
    const float* ln2b = (const float*)d_in[17];
    float* out = (float*)d_out;
    char* ws = (char*)d_ws;

    const size_t o_srcb = 0;                       // 8 MB   bf16 src; later reused as xb
    const size_t o_wtqkv = o_srcb + 8388608;       // 6 MB
    const size_t o_wto = o_wtqkv + 6291456;        // 2 MB
    const size_t o_wt1 = o_wto + 2097152;          // 8 MB
    const size_t o_wt2 = o_wt1 + 8388608;          // 8 MB
    const size_t o_bqkv = o_wt2 + 8388608;         // 12 KB
    const size_t o_qkv = o_bqkv + 12288;           // 24 MB  qkv bf16; later reused as attnout/ff fp32
    const size_t o_ctxb = o_qkv + 25165824;        // 8 MB
    const size_t o_x = o_ctxb + 8388608;           // 16 MB
    const size_t o_hb = o_x + 16777216;            // 32 MB

    unsigned short* srcb = (unsigned short*)(ws + o_srcb);
    unsigned short* wtqkv = (unsigned short*)(ws + o_wtqkv);
    unsigned short* wto = (unsigned short*)(ws + o_wto);
    unsigned short* wt1 = (unsigned short*)(ws + o_wt1);
    unsigned short* wt2 = (unsigned short*)(ws + o_wt2);
    float* bqkv = (float*)(ws + o_bqkv);
    unsigned short* qkvb = (unsigned short*)(ws + o_qkv);
    unsigned short* ctxb = (unsigned short*)(ws + o_ctxb);
    float* x = (float*)(ws + o_x);
    unsigned short* hb = (unsigned short*)(ws + o_hb);
    float* attnout = (float*)(ws + o_qkv);
    float* ff = (float*)(ws + o_qkv);
    unsigned short* xb = (unsigned short*)(ws + o_srcb);

    cast_bf16_kernel<<<4096, 256, 0, stream>>>(src, srcb, 1048576);
    transpose_cast_kernel<<<dim3(32, 32), 256, 0, stream>>>(Wq, wtqkv, 1024, 1024);
    transpose_cast_kernel<<<dim3(32, 32), 256, 0, stream>>>(Wk, wtqkv + 1024 * 1024, 1024, 1024);
    transpose_cast_kernel<<<dim3(32, 32), 256, 0, stream>>>(Wv, wtqkv + 2 * 1024 * 1024, 1024, 1024);
    transpose_cast_kernel<<<dim3(32, 32), 256, 0, stream>>>(Wo, wto, 1024, 1024);
    transpose_cast_kernel<<<dim3(128, 32), 256, 0, stream>>>(W1, wt1, 1024, 4096);
    transpose_cast_kernel<<<dim3(32, 128), 256, 0, stream>>>(W2, wt2, 4096, 1024);
    pack_bias_kernel<<<12, 256, 0, stream>>>(bq, bk, bv, bqkv);

    gemm_kernel<4, true, false><<<dim3(24, 32), 256, 0, stream>>>(srcb, wtqkv, bqkv, qkvb, NROW, 3072, 1024);
    attn_kernel<<<1024, 256, 0, stream>>>(qkvb, rpe, ctxb);
    gemm_kernel<2, false, false><<<dim3(16, 32), 256, 0, stream>>>(ctxb, wto, bo, attnout, NROW, 1024, 1024);
    resln_kernel<true><<<4096, 256, 0, stream>>>(src, attnout, ln1g, ln1b, x, xb);
    gemm_kernel<4, true, true><<<dim3(32, 32), 256, 0, stream>>>(xb, wt1, b1, hb, NROW, 4096, 1024);
    gemm_kernel<2, false, false><<<dim3(16, 32), 256, 0, stream>>>(hb, wt2, b2, ff, NROW, 1024, 4096);
    resln_kernel<false><<<4096, 256, 0, stream>>>(x, ff, ln2g, ln2b, out, nullptr);
}

// Round 5
// 346.286 us; speedup vs baseline: 1.3676x; 1.3373x over previous
//
#include <hip/hip_runtime.h>
#include <hip/hip_bf16.h>

#define D_MODEL 1024
#define NHEAD 16
#define DH 64
#define DFF 4096
#define MAXD 32
#define L_ 2048
#define NROW 4096

typedef __attribute__((ext_vector_type(4))) float floatx4;
typedef __attribute__((ext_vector_type(8))) __bf16 bf16x8;
typedef __attribute__((ext_vector_type(4))) unsigned short ushort4v;

static __device__ inline unsigned short f2bf(float f) {
    __hip_bfloat16 h = __float2bfloat16(f);
    return __builtin_bit_cast(unsigned short, h);
}

static __device__ inline floatx4 mfma16(bf16x8 a, bf16x8 b, floatx4 c) {
    return __builtin_amdgcn_mfma_f32_16x16x32_bf16(a, b, c, 0, 0, 0);
}

static __device__ inline void gload_lds16(const unsigned short* g, unsigned short* l) {
    __builtin_amdgcn_global_load_lds((const __attribute__((address_space(1))) unsigned int*)g,
                                     (__attribute__((address_space(3))) unsigned int*)l,
                                     16, 0, 0);
}

// ---------------- elementwise cast fp32 -> bf16 ----------------
__global__ __launch_bounds__(256) void cast_bf16_kernel(const float* __restrict__ in,
                                                        unsigned short* __restrict__ out, int n4) {
    int i = blockIdx.x * 256 + threadIdx.x;
    if (i < n4) {
        floatx4 v = *(const floatx4*)&in[(size_t)i * 4];
        ushort4v o;
        o.x = f2bf(v[0]); o.y = f2bf(v[1]); o.z = f2bf(v[2]); o.w = f2bf(v[3]);
        *(ushort4v*)&out[(size_t)i * 4] = o;
    }
}

// ---------------- transpose + cast: W fp32 [K][N] -> WT bf16 [N][K] ----------------
__global__ __launch_bounds__(256) void transpose_cast_kernel(const float* __restrict__ W,
                                                             unsigned short* __restrict__ WT,
                                                             int K, int N) {
    __shared__ float tile[32][33];
    int k0 = blockIdx.y * 32, n0 = blockIdx.x * 32;
    for (int i = threadIdx.x; i < 1024; i += 256) {
        int r = i >> 5, c = i & 31;
        tile[r][c] = W[(size_t)(k0 + r) * N + n0 + c];
    }
    __syncthreads();
    for (int i = threadIdx.x; i < 1024; i += 256) {
        int r = i >> 5, c = i & 31;
        WT[(size_t)(n0 + r) * K + k0 + c] = f2bf(tile[c][r]);
    }
}

// ---------------- pack qkv bias ----------------
__global__ __launch_bounds__(256) void pack_bias_kernel(const float* __restrict__ bq,
                                                        const float* __restrict__ bk,
                                                        const float* __restrict__ bv,
                                                        float* __restrict__ out) {
    int i = blockIdx.x * 256 + threadIdx.x;
    if (i < 3072) out[i] = (i < 1024) ? bq[i] : ((i < 2048) ? bk[i - 1024] : bv[i - 2048]);
}

// ---------------- GEMM: C[M][N] = A[M][K] @ BT[N][K]^T + bias ----------------
template <int NF, bool OUTBF16, bool RELU>
__global__ __launch_bounds__(256) void gemm_kernel(const unsigned short* __restrict__ A,
                                                   const unsigned short* __restrict__ BT,
                                                   const float* __restrict__ bias,
                                                   void* __restrict__ Cout,
                                                   int M, int N, int K) {
    constexpr int BN = NF * 32;
    __shared__ unsigned short Asm[128][32];
    __shared__ unsigned short Bsm[BN][32];
    int t = threadIdx.x;
    int lane = t & 63, w = t >> 6;
    int wm = w >> 1, wn = w & 1;
    int lr = lane & 15, hg = lane >> 4;
    int m0 = blockIdx.y * 128, n0 = blockIdx.x * BN;

    floatx4 acc[4][NF];
#pragma unroll
    for (int i = 0; i < 4; i++)
#pragma unroll
        for (int j = 0; j < NF; j++) acc[i][j] = (floatx4)0.0f;

    int r0 = t >> 2, c0 = (t & 3) * 8;

    for (int k0 = 0; k0 < K; k0 += 32) {
        __syncthreads();
        gload_lds16(&A[(size_t)(m0 + r0) * K + k0 + c0], &Asm[r0][c0]);
        gload_lds16(&A[(size_t)(m0 + r0 + 64) * K + k0 + c0], &Asm[r0 + 64][c0]);
        gload_lds16(&BT[(size_t)(n0 + r0) * K + k0 + c0], &Bsm[r0][c0]);
        if (NF == 4)
            gload_lds16(&BT[(size_t)(n0 + r0 + 64) * K + k0 + c0], &Bsm[r0 + 64][c0]);
        __syncthreads();
        bf16x8 af[4], bfg[NF];
#pragma unroll
        for (int mf = 0; mf < 4; mf++) af[mf] = *(const bf16x8*)&Asm[wm * 64 + mf * 16 + lr][hg * 8];
#pragma unroll
        for (int nf = 0; nf < NF; nf++)
            bfg[nf] = *(const bf16x8*)&Bsm[wn * NF * 16 + nf * 16 + lr][hg * 8];
#pragma unroll
        for (int mf = 0; mf < 4; mf++)
#pragma unroll
            for (int nf = 0; nf < NF; nf++) acc[mf][nf] = mfma16(af[mf], bfg[nf], acc[mf][nf]);
    }

#pragma unroll
    for (int mf = 0; mf < 4; mf++)
#pragma unroll
        for (int nf = 0; nf < NF; nf++) {
            int col = n0 + wn * NF * 16 + nf * 16 + lr;
            float bv = bias[col];
#pragma unroll
            for (int r = 0; r < 4; r++) {
                int row = m0 + wm * 64 + mf * 16 + hg * 4 + r;
                float v = acc[mf][nf][r] + bv;
                if (RELU) v = v > 0.f ? v : 0.f;
                if (OUTBF16)
                    ((unsigned short*)Cout)[(size_t)row * N + col] = f2bf(v);
                else
                    ((float*)Cout)[(size_t)row * N + col] = v;
            }
        }
}

// ---------------- fused attention, swapped-QK^T / in-lane softmax ----------------
// 512 blocks x 512 threads; 8 waves, each owns 16 q-columns (128 q rows/block).
// S^T = mfma(K,Q): lane holds S[k= kf*16+hg*4+r][q= w*16+lr]. Softmax in-lane (2 shfl).
// P -> wave-private LDS tile [16 q][64 k] (8 packed b32 writes), PV: O^T = mfma(V^T,P^T).
// All LDS tiles 64-short rows, chunk-XOR swizzle: chunk ^= (row ^ row>>3)&7.
__global__ __launch_bounds__(512, 4) void attn_kernel(const unsigned short* __restrict__ qkv, // [4096][3072]
                                                      const float* __restrict__ rpe,          // [65][16]
                                                      unsigned short* __restrict__ ctx) {     // [4096][1024]
    __shared__ unsigned short Kb0[64 * 64];
    __shared__ unsigned short Kb1[64 * 64];
    __shared__ unsigned short Vt[64 * 64];      // V^T: [d][k_local]
    __shared__ unsigned short Ps[8][16 * 64];   // per-wave P^T as [q][k_local]
    __shared__ float rpl[65];

    const int t = threadIdx.x;
    const int lane = t & 63, w = t >> 6;
    const int lr = lane & 15, hg = lane >> 4;
    const int lrs = (lr & 7) ^ (lr >> 3);       // SWZ of rows == lr (mod 8-chunk space)

    const int blk = blockIdx.x;
    const int qb = blk & 15;
    const int h = (blk >> 4) & 15;
    const int b = blk >> 8;
    const int q0 = qb * 128;
    const int hcol = h * 64;
    const size_t rowbase = (size_t)b * L_ * 3072;

    const int kr = t >> 3, kch = t & 7;                         // staging coords (64 rows x 8 chunks)
    const int kswz = (kch ^ (kr & 7) ^ (kr >> 3)) & 7;          // pre-swizzled global chunk for K
    unsigned short* kdst0 = &Kb0[kr * 64 + kch * 8];
    unsigned short* kdst1 = &Kb1[kr * 64 + kch * 8];

    if (t < 65) rpl[t] = rpe[t * NHEAD + h];

    // Q direct to registers: B-frag = Q[q][d = kc*32 + hg*8 + e]
    const int qi = q0 + w * 16 + lr;
    bf16x8 qf0 = *(const bf16x8*)&qkv[rowbase + (size_t)qi * 3072 + hcol + hg * 8];
    bf16x8 qf1 = *(const bf16x8*)&qkv[rowbase + (size_t)qi * 3072 + hcol + 32 + hg * 8];

    // prologue: stage K tile 0 (swizzled source -> linear LDS dest)
    gload_lds16(&qkv[rowbase + (size_t)kr * 3072 + 1024 + hcol + kswz * 8], kdst0);
    __syncthreads();

    float rpl0 = rpl[0], rpl64 = rpl[64];
    floatx4 o[4];
#pragma unroll
    for (int df = 0; df < 4; df++) o[df] = (floatx4)0.f;
    float mst = -1e30f, lst = 0.f;
    const float scale = 0.125f;
    unsigned short* PsW = &Ps[w][0];

#define ATT_STEP(KT, KcP, KnP, MORE)                                                               \
    {                                                                                              \
        const int key0 = (KT) * 64;                                                                \
        int4 tv = *(const int4*)&qkv[rowbase + (size_t)(key0 + kr) * 3072 + 2048 + hcol + kch * 8];\
        if (MORE)                                                                                  \
            gload_lds16(&qkv[rowbase + (size_t)(key0 + 64 + kr) * 3072 + 1024 + hcol + kswz * 8],  \
                        KnP);                                                                      \
        floatx4 st[4];                                                                             \
        _Pragma("unroll")                                                                          \
        for (int kf = 0; kf < 4; kf++) {                                                           \
            int sw = lrs ^ (kf * 2);                                                               \
            bf16x8 a0 = *(const bf16x8*)&(KcP)[(kf * 16 + lr) * 64 + ((hg ^ sw) << 3)];            \
            bf16x8 a1 = *(const bf16x8*)&(KcP)[(kf * 16 + lr) * 64 + (((4 + hg) ^ sw) << 3)];      \
            st[kf] = mfma16(a1, qf1, mfma16(a0, qf0, (floatx4)0.f));                               \
        }                                                                                          \
        bool rightC = (key0 > q0 + 159);                                                           \
        bool leftC = (key0 + 95 < q0);                                                             \
        float cbv = rightC ? rpl64 : rpl0;                                                         \
        float sv[16];                                                                              \
        float mx = -1e30f;                                                                         \
        if (leftC || rightC) {                                                                     \
            _Pragma("unroll")                                                                      \
            for (int kf = 0; kf < 4; kf++)                                                         \
                _Pragma("unroll")                                                                  \
                for (int r = 0; r < 4; r++) {                                                      \
                    float v = st[kf][r] * scale + cbv;                                             \
                    sv[kf * 4 + r] = v;                                                            \
                    mx = fmaxf(mx, v);                                                             \
                }                                                                                  \
        } else {                                                                                   \
            _Pragma("unroll")                                                                      \
            for (int kf = 0; kf < 4; kf++)                                                         \
                _Pragma("unroll")                                                                  \
                for (int r = 0; r < 4; r++) {                                                      \
                    int rel = key0 + kf * 16 + hg * 4 + r - qi;                                    \
                    rel = rel < -MAXD ? -MAXD : (rel > MAXD ? MAXD : rel);                         \
                    float v = st[kf][r] * scale + rpl[rel + MAXD];                                 \
                    sv[kf * 4 + r] = v;                                                            \
                    mx = fmaxf(mx, v);                                                             \
                }                                                                                  \
        }                                                                                          \
        mx = fmaxf(mx, __shfl_xor(mx, 16, 64));                                                    \
        mx = fmaxf(mx, __shfl_xor(mx, 32, 64));                                                    \
        float newm = fmaxf(mst, mx);                                                               \
        float corr = __expf(mst - newm);                                                           \
        mst = newm;                                                                                \
        float ps = 0.f;                                                                            \
        unsigned int pk[8];                                                                        \
        _Pragma("unroll")                                                                          \
        for (int kf = 0; kf < 4; kf++)                                                             \
            _Pragma("unroll")                                                                      \
            for (int j = 0; j < 2; j++) {                                                          \
                float p0 = __expf(sv[kf * 4 + 2 * j] - newm);                                      \
                float p1 = __expf(sv[kf * 4 + 2 * j + 1] - newm);                                  \
                ps += p0 + p1;                                                                     \
                pk[kf * 2 + j] = (unsigned int)f2bf(p0) | ((unsigned int)f2bf(p1) << 16);          \
            }                                                                                      \
        lst = lst * corr + ps;                                                                     \
        _Pragma("unroll")                                                                          \
        for (int df = 0; df < 4; df++) o[df] *= corr;                                              \
        _Pragma("unroll")                                                                          \
        for (int kf = 0; kf < 4; kf++)                                                             \
            _Pragma("unroll")                                                                      \
            for (int j = 0; j < 2; j++) {                                                          \
                int ch = ((kf * 2 + (hg >> 1)) ^ lrs) & 7;                                         \
                *(unsigned int*)&PsW[lr * 64 + (ch << 3) + (hg & 1) * 4 + 2 * j] = pk[kf * 2 + j]; \
            }                                                                                      \
        _Pragma("unroll")                                                                          \
        for (int e = 0; e < 8; e++) {                                                              \
            int d = kch * 8 + e;                                                                   \
            int ch = ((kr >> 3) ^ e ^ kch) & 7;                                                    \
            unsigned short val = (unsigned short)(((const unsigned int*)&tv)[e >> 1] >>            \
                                                  ((e & 1) * 16));                                 \
            Vt[d * 64 + (ch << 3) + (kr & 7)] = val;                                               \
        }                                                                                          \
        __syncthreads();                                                                           \
        bf16x8 pb0 = *(const bf16x8*)&PsW[lr * 64 + ((hg ^ lrs) << 3)];                            \
        bf16x8 pb1 = *(const bf16x8*)&PsW[lr * 64 + (((4 + hg) ^ lrs) << 3)];                      \
        _Pragma("unroll")                                                                          \
        for (int df = 0; df < 4; df++) {                                                           \
            int sw = lrs ^ (df * 2);                                                               \
            bf16x8 v0 = *(const bf16x8*)&Vt[(df * 16 + lr) * 64 + ((hg ^ sw) << 3)];               \
            bf16x8 v1 = *(const bf16x8*)&Vt[(df * 16 + lr) * 64 + (((4 + hg) ^ sw) << 3)];         \
            o[df] = mfma16(v1, pb1, mfma16(v0, pb0, o[df]));                                       \
        }                                                                                          \
        __syncthreads();                                                                           \
    }

    for (int kt = 0; kt < L_ / 64; kt += 2) {
        ATT_STEP(kt, Kb0, kdst1, true);
        ATT_STEP(kt + 1, Kb1, kdst0, (kt + 2 < L_ / 64));
    }
#undef ATT_STEP

    // final: reduce per-lane partial sums across the 4 hg groups, write O^T scatter
    float rs = lst;
    rs += __shfl_xor(rs, 16, 64);
    rs += __shfl_xor(rs, 32, 64);
    float inv = 1.f / rs;
    size_t obase = (size_t)(b * L_ + qi) * 1024 + hcol;
#pragma unroll
    for (int df = 0; df < 4; df++)
#pragma unroll
        for (int r = 0; r < 4; r++)
            ctx[obase + df * 16 + hg * 4 + r] = f2bf(o[df][r] * inv);
}

// ---------------- fused residual + layernorm ----------------
template <bool WBF>
__global__ __launch_bounds__(256) void resln_kernel(const float* __restrict__ ra,
                                                    const float* __restrict__ rb,
                                                    const float* __restrict__ g,
                                                    const float* __restrict__ be,
                                                    float* __restrict__ outf,
                                                    unsigned short* __restrict__ outb) {
    __shared__ float red[4];
    __shared__ float red2[4];
    int row = blockIdx.x;
    int t = threadIdx.x;
    int w = t >> 6, lane = t & 63;
    size_t base = (size_t)row * 1024 + t * 4;
    floatx4 a = *(const floatx4*)&ra[base];
    floatx4 b = *(const floatx4*)&rb[base];
    floatx4 y = a + b;
    float s = y[0] + y[1] + y[2] + y[3];
#pragma unroll
    for (int d = 1; d < 64; d <<= 1) s += __shfl_xor(s, d, 64);
    if (lane == 0) red[w] = s;
    __syncthreads();
    float mu = (red[0] + red[1] + red[2] + red[3]) * (1.f / 1024.f);
    floatx4 d4 = y - mu;
    float sq = d4[0] * d4[0] + d4[1] * d4[1] + d4[2] * d4[2] + d4[3] * d4[3];
#pragma unroll
    for (int d = 1; d < 64; d <<= 1) sq += __shfl_xor(sq, d, 64);
    if (lane == 0) red2[w] = sq;
    __syncthreads();
    float var = (red2[0] + red2[1] + red2[2] + red2[3]) * (1.f / 1024.f);
    float rstd = rsqrtf(var + 1e-5f);
    floatx4 gg = *(const floatx4*)&g[t * 4];
    floatx4 bb = *(const floatx4*)&be[t * 4];
    floatx4 outv;
#pragma unroll
    for (int i = 0; i < 4; i++) outv[i] = d4[i] * rstd * gg[i] + bb[i];
    *(floatx4*)&outf[base] = outv;
    if (WBF) {
        ushort4v ov;
        ov.x = f2bf(outv[0]); ov.y = f2bf(outv[1]); ov.z = f2bf(outv[2]); ov.w = f2bf(outv[3]);
        *(ushort4v*)&outb[base] = ov;
    }
}

extern "C" void kernel_launch(void* const* d_in, const int* in_sizes, int n_in,
                              void* d_out, int out_size, void* d_ws, size_t ws_size,
                              hipStream_t stream) {
    const float* src = (const float*)d_in[0];
    const float* Wq = (const float*)d_in[1];
    const float* Wk = (const float*)d_in[2];
    const float* Wv = (const float*)d_in[3];
    const float* bq = (const float*)d_in[4];
    const float* bk = (const float*)d_in[5];
    const float* bv = (const float*)d_in[6];
    const float* Wo = (const float*)d_in[7];
    const float* bo = (const float*)d_in[8];
    const float* rpe = (const float*)d_in[9];
    const float* W1 = (const float*)d_in[10];
    const float* b1 = (const float*)d_in[11];
    const float* W2 = (const float*)d_in[12];
    const float* b2 = (const float*)d_in[13];
    const float* ln1g = (const float*)d_in[14];
    const float* ln1b = (const float*)d_in[15];
    const float* ln2g = (const float*)d_in[16];
    const float* ln2b = (const float*)d_in[17];
    float* out = (float*)d_out;
    char* ws = (char*)d_ws;

    const size_t o_srcb = 0;                       // 8 MB   bf16 src; later reused as xb
    const size_t o_wtqkv = o_srcb + 8388608;       // 6 MB
    const size_t o_wto = o_wtqkv + 6291456;        // 2 MB
    const size_t o_wt1 = o_wto + 2097152;          // 8 MB
    const size_t o_wt2 = o_wt1 + 8388608;          // 8 MB
    const size_t o_bqkv = o_wt2 + 8388608;         // 12 KB
    const size_t o_qkv = o_bqkv + 12288;           // 24 MB  qkv bf16; later reused as attnout/ff fp32
    const size_t o_ctxb = o_qkv + 25165824;        // 8 MB
    const size_t o_x = o_ctxb + 8388608;           // 16 MB
    const size_t o_hb = o_x + 16777216;            // 32 MB

    unsigned short* srcb = (unsigned short*)(ws + o_srcb);
    unsigned short* wtqkv = (unsigned short*)(ws + o_wtqkv);
    unsigned short* wto = (unsigned short*)(ws + o_wto);
    unsigned short* wt1 = (unsigned short*)(ws + o_wt1);
    unsigned short* wt2 = (unsigned short*)(ws + o_wt2);
    float* bqkv = (float*)(ws + o_bqkv);
    unsigned short* qkvb = (unsigned short*)(ws + o_qkv);
    unsigned short* ctxb = (unsigned short*)(ws + o_ctxb);
    float* x = (float*)(ws + o_x);
    unsigned short* hb = (unsigned short*)(ws + o_hb);
    float* attnout = (float*)(ws + o_qkv);
    float* ff = (float*)(ws + o_qkv);
    unsigned short* xb = (unsigned short*)(ws + o_srcb);

    cast_bf16_kernel<<<4096, 256, 0, stream>>>(src, srcb, 1048576);
    transpose_cast_kernel<<<dim3(32, 32), 256, 0, stream>>>(Wq, wtqkv, 1024, 1024);
    transpose_cast_kernel<<<dim3(32, 32), 256, 0, stream>>>(Wk, wtqkv + 1024 * 1024, 1024, 1024);
    transpose_cast_kernel<<<dim3(32, 32), 256, 0, stream>>>(Wv, wtqkv + 2 * 1024 * 1024, 1024, 1024);
    transpose_cast_kernel<<<dim3(32, 32), 256, 0, stream>>>(Wo, wto, 1024, 1024);
    transpose_cast_kernel<<<dim3(128, 32), 256, 0, stream>>>(W1, wt1, 1024, 4096);
    transpose_cast_kernel<<<dim3(32, 128), 256, 0, stream>>>(W2, wt2, 4096, 1024);
    pack_bias_kernel<<<12, 256, 0, stream>>>(bq, bk, bv, bqkv);

    gemm_kernel<4, true, false><<<dim3(24, 32), 256, 0, stream>>>(srcb, wtqkv, bqkv, qkvb, NROW, 3072, 1024);
    attn_kernel<<<512, 512, 0, stream>>>(qkvb, rpe, ctxb);
    gemm_kernel<2, false, false><<<dim3(16, 32), 256, 0, stream>>>(ctxb, wto, bo, attnout, NROW, 1024, 1024);
    resln_kernel<true><<<4096, 256, 0, stream>>>(src, attnout, ln1g, ln1b, x, xb);
    gemm_kernel<4, true, true><<<dim3(32, 32), 256, 0, stream>>>(xb, wt1, b1, hb, NROW, 4096, 1024);
    gemm_kernel<2, false, false><<<dim3(16, 32), 256, 0, stream>>>(hb, wt2, b2, ff, NROW, 1024, 4096);
    resln_kernel<false><<<4096, 256, 0, stream>>>(x, ff, ln2g, ln2b, out, nullptr);
}

// Round 6
// 309.956 us; speedup vs baseline: 1.5279x; 1.1172x over previous
//
#include <hip/hip_runtime.h>
#include <hip/hip_bf16.h>

#define D_MODEL 1024
#define NHEAD 16
#define DH 64
#define DFF 4096
#define MAXD 32
#define L_ 2048
#define NROW 4096

typedef __attribute__((ext_vector_type(4))) float floatx4;
typedef __attribute__((ext_vector_type(8))) __bf16 bf16x8;
typedef __attribute__((ext_vector_type(4))) unsigned short ushort4v;

static __device__ inline unsigned short f2bf(float f) {
    __hip_bfloat16 h = __float2bfloat16(f);
    return __builtin_bit_cast(unsigned short, h);
}

static __device__ inline floatx4 mfma16(bf16x8 a, bf16x8 b, floatx4 c) {
    return __builtin_amdgcn_mfma_f32_16x16x32_bf16(a, b, c, 0, 0, 0);
}

static __device__ inline void gload_lds16(const unsigned short* g, unsigned short* l) {
    __builtin_amdgcn_global_load_lds((const __attribute__((address_space(1))) unsigned int*)g,
                                     (__attribute__((address_space(3))) unsigned int*)l,
                                     16, 0, 0);
}

// ---------------- elementwise cast fp32 -> bf16 ----------------
__global__ __launch_bounds__(256) void cast_bf16_kernel(const float* __restrict__ in,
                                                        unsigned short* __restrict__ out, int n4) {
    int i = blockIdx.x * 256 + threadIdx.x;
    if (i < n4) {
        floatx4 v = *(const floatx4*)&in[(size_t)i * 4];
        ushort4v o;
        o.x = f2bf(v[0]); o.y = f2bf(v[1]); o.z = f2bf(v[2]); o.w = f2bf(v[3]);
        *(ushort4v*)&out[(size_t)i * 4] = o;
    }
}

// ---------------- transpose + cast: W fp32 [K][N] -> WT bf16 [N][K] ----------------
__global__ __launch_bounds__(256) void transpose_cast_kernel(const float* __restrict__ W,
                                                             unsigned short* __restrict__ WT,
                                                             int K, int N) {
    __shared__ float tile[32][33];
    int k0 = blockIdx.y * 32, n0 = blockIdx.x * 32;
    for (int i = threadIdx.x; i < 1024; i += 256) {
        int r = i >> 5, c = i & 31;
        tile[r][c] = W[(size_t)(k0 + r) * N + n0 + c];
    }
    __syncthreads();
    for (int i = threadIdx.x; i < 1024; i += 256) {
        int r = i >> 5, c = i & 31;
        WT[(size_t)(n0 + r) * K + k0 + c] = f2bf(tile[c][r]);
    }
}

// ---------------- pack qkv bias ----------------
__global__ __launch_bounds__(256) void pack_bias_kernel(const float* __restrict__ bq,
                                                        const float* __restrict__ bk,
                                                        const float* __restrict__ bv,
                                                        float* __restrict__ out) {
    int i = blockIdx.x * 256 + threadIdx.x;
    if (i < 3072) out[i] = (i < 1024) ? bq[i] : ((i < 2048) ? bk[i - 1024] : bv[i - 2048]);
}

// ---------------- GEMM: C[M][N] = A[M][K] @ BT[N][K]^T + bias ----------------
// 128 x (NF*32) tile, 4 waves, BK=64 (32 MFMA/wave per step, half the barrier drains).
// LDS rows are 128B -> mandatory chunk-XOR swizzle: chunk' = chunk ^ (row&7),
// applied on the pre-swizzled GLOBAL source (gload_lds dest stays linear) and on reads.
template <int NF, bool OUTBF16, bool RELU>
__global__ __launch_bounds__(256) void gemm_kernel(const unsigned short* __restrict__ A,
                                                   const unsigned short* __restrict__ BT,
                                                   const float* __restrict__ bias,
                                                   void* __restrict__ Cout,
                                                   int M, int N, int K) {
    constexpr int BN = NF * 32;
    __shared__ unsigned short Asm[128][64];
    __shared__ unsigned short Bsm[BN][64];
    int t = threadIdx.x;
    int lane = t & 63, w = t >> 6;
    int wm = w >> 1, wn = w & 1;
    int lr = lane & 15, hg = lane >> 4;
    int m0 = blockIdx.y * 128, n0 = blockIdx.x * BN;

    floatx4 acc[4][NF];
#pragma unroll
    for (int i = 0; i < 4; i++)
#pragma unroll
        for (int j = 0; j < NF; j++) acc[i][j] = (floatx4)0.0f;

    const int lr7 = lr & 7;

    for (int k0 = 0; k0 < K; k0 += 64) {
        __syncthreads();
#pragma unroll
        for (int i = 0; i < 4; i++) {
            int c = t + i * 256;               // 1024 chunks: 128 rows x 8
            int r = c >> 3, ch = c & 7;
            int chs = ch ^ (r & 7);
            gload_lds16(&A[(size_t)(m0 + r) * K + k0 + chs * 8], &Asm[r][ch * 8]);
        }
#pragma unroll
        for (int i = 0; i < BN / 32; i++) {    // BN*8 chunks
            int c = t + i * 256;
            int r = c >> 3, ch = c & 7;
            int chs = ch ^ (r & 7);
            gload_lds16(&BT[(size_t)(n0 + r) * K + k0 + chs * 8], &Bsm[r][ch * 8]);
        }
        __syncthreads();
#pragma unroll
        for (int kc = 0; kc < 2; kc++) {
            int ch = (kc * 4 + hg) ^ lr7;
            bf16x8 af[4], bfg[NF];
#pragma unroll
            for (int mf = 0; mf < 4; mf++)
                af[mf] = *(const bf16x8*)&Asm[wm * 64 + mf * 16 + lr][ch * 8];
#pragma unroll
            for (int nf = 0; nf < NF; nf++)
                bfg[nf] = *(const bf16x8*)&Bsm[wn * NF * 16 + nf * 16 + lr][ch * 8];
#pragma unroll
            for (int mf = 0; mf < 4; mf++)
#pragma unroll
                for (int nf = 0; nf < NF; nf++) acc[mf][nf] = mfma16(af[mf], bfg[nf], acc[mf][nf]);
        }
    }

#pragma unroll
    for (int mf = 0; mf < 4; mf++)
#pragma unroll
        for (int nf = 0; nf < NF; nf++) {
            int col = n0 + wn * NF * 16 + nf * 16 + lr;
            float bv = bias[col];
#pragma unroll
            for (int r = 0; r < 4; r++) {
                int row = m0 + wm * 64 + mf * 16 + hg * 4 + r;
                float v = acc[mf][nf][r] + bv;
                if (RELU) v = v > 0.f ? v : 0.f;
                if (OUTBF16)
                    ((unsigned short*)Cout)[(size_t)row * N + col] = f2bf(v);
                else
                    ((float*)Cout)[(size_t)row * N + col] = v;
            }
        }
}

// ---------------- fused attention, swapped-QK^T / in-lane softmax ----------------
// 512 blocks x 512 threads; 8 waves, each owns 16 q-columns (128 q rows/block).
// XCD-chunked block swizzle: 64 consecutive logical blocks (4 whole heads) per XCD
// so each XCD's L2 holds its heads' K/V (2 MB < 4 MB).
__global__ __launch_bounds__(512, 4) void attn_kernel(const unsigned short* __restrict__ qkv, // [4096][3072]
                                                      const float* __restrict__ rpe,          // [65][16]
                                                      unsigned short* __restrict__ ctx) {     // [4096][1024]
    __shared__ unsigned short Kb0[64 * 64];
    __shared__ unsigned short Kb1[64 * 64];
    __shared__ unsigned short Vt[64 * 64];      // V^T: [d][k_local]
    __shared__ unsigned short Ps[8][16 * 64];   // per-wave P^T as [q][k_local]
    __shared__ float rpl[65];

    const int t = threadIdx.x;
    const int lane = t & 63, w = t >> 6;
    const int lr = lane & 15, hg = lane >> 4;
    const int lrs = (lr & 7) ^ (lr >> 3);

    const int g = blockIdx.x;
    const int blk = (g & 7) * 64 + (g >> 3);    // bijective XCD-chunk swizzle (512 = 8*64)
    const int qb = blk & 15;
    const int h = (blk >> 4) & 15;
    const int b = blk >> 8;
    const int q0 = qb * 128;
    const int hcol = h * 64;
    const size_t rowbase = (size_t)b * L_ * 3072;

    const int kr = t >> 3, kch = t & 7;
    const int kswz = (kch ^ (kr & 7) ^ (kr >> 3)) & 7;
    unsigned short* kdst0 = &Kb0[kr * 64 + kch * 8];
    unsigned short* kdst1 = &Kb1[kr * 64 + kch * 8];

    if (t < 65) rpl[t] = rpe[t * NHEAD + h];

    const int qi = q0 + w * 16 + lr;
    bf16x8 qf0 = *(const bf16x8*)&qkv[rowbase + (size_t)qi * 3072 + hcol + hg * 8];
    bf16x8 qf1 = *(const bf16x8*)&qkv[rowbase + (size_t)qi * 3072 + hcol + 32 + hg * 8];

    gload_lds16(&qkv[rowbase + (size_t)kr * 3072 + 1024 + hcol + kswz * 8], kdst0);
    __syncthreads();

    float rpl0 = rpl[0], rpl64 = rpl[64];
    floatx4 o[4];
#pragma unroll
    for (int df = 0; df < 4; df++) o[df] = (floatx4)0.f;
    float mst = -1e30f, lst = 0.f;
    const float scale = 0.125f;
    unsigned short* PsW = &Ps[w][0];

#define ATT_STEP(KT, KcP, KnP, MORE)                                                               \
    {                                                                                              \
        const int key0 = (KT) * 64;                                                                \
        int4 tv = *(const int4*)&qkv[rowbase + (size_t)(key0 + kr) * 3072 + 2048 + hcol + kch * 8];\
        if (MORE)                                                                                  \
            gload_lds16(&qkv[rowbase + (size_t)(key0 + 64 + kr) * 3072 + 1024 + hcol + kswz * 8],  \
                        KnP);                                                                      \
        floatx4 st[4];                                                                             \
        _Pragma("unroll")                                                                          \
        for (int kf = 0; kf < 4; kf++) {                                                           \
            int sw = lrs ^ (kf * 2);                                                               \
            bf16x8 a0 = *(const bf16x8*)&(KcP)[(kf * 16 + lr) * 64 + ((hg ^ sw) << 3)];            \
            bf16x8 a1 = *(const bf16x8*)&(KcP)[(kf * 16 + lr) * 64 + (((4 + hg) ^ sw) << 3)];      \
            st[kf] = mfma16(a1, qf1, mfma16(a0, qf0, (floatx4)0.f));                               \
        }                                                                                          \
        bool rightC = (key0 > q0 + 159);                                                           \
        bool leftC = (key0 + 95 < q0);                                                             \
        float cbv = rightC ? rpl64 : rpl0;                                                         \
        float sv[16];                                                                              \
        float mx = -1e30f;                                                                         \
        if (leftC || rightC) {                                                                     \
            _Pragma("unroll")                                                                      \
            for (int kf = 0; kf < 4; kf++)                                                         \
                _Pragma("unroll")                                                                  \
                for (int r = 0; r < 4; r++) {                                                      \
                    float v = st[kf][r] * scale + cbv;                                             \
                    sv[kf * 4 + r] = v;                                                            \
                    mx = fmaxf(mx, v);                                                             \
                }                                                                                  \
        } else {                                                                                   \
            _Pragma("unroll")                                                                      \
            for (int kf = 0; kf < 4; kf++)                                                         \
                _Pragma("unroll")                                                                  \
                for (int r = 0; r < 4; r++) {                                                      \
                    int rel = key0 + kf * 16 + hg * 4 + r - qi;                                    \
                    rel = rel < -MAXD ? -MAXD : (rel > MAXD ? MAXD : rel);                         \
                    float v = st[kf][r] * scale + rpl[rel + MAXD];                                 \
                    sv[kf * 4 + r] = v;                                                            \
                    mx = fmaxf(mx, v);                                                             \
                }                                                                                  \
        }                                                                                          \
        mx = fmaxf(mx, __shfl_xor(mx, 16, 64));                                                    \
        mx = fmaxf(mx, __shfl_xor(mx, 32, 64));                                                    \
        float newm = fmaxf(mst, mx);                                                               \
        float corr = __expf(mst - newm);                                                           \
        mst = newm;                                                                                \
        float ps = 0.f;                                                                            \
        unsigned int pk[8];                                                                        \
        _Pragma("unroll")                                                                          \
        for (int kf = 0; kf < 4; kf++)                                                             \
            _Pragma("unroll")                                                                      \
            for (int j = 0; j < 2; j++) {                                                          \
                float p0 = __expf(sv[kf * 4 + 2 * j] - newm);                                      \
                float p1 = __expf(sv[kf * 4 + 2 * j + 1] - newm);                                  \
                ps += p0 + p1;                                                                     \
                pk[kf * 2 + j] = (unsigned int)f2bf(p0) | ((unsigned int)f2bf(p1) << 16);          \
            }                                                                                      \
        lst = lst * corr + ps;                                                                     \
        _Pragma("unroll")                                                                          \
        for (int df = 0; df < 4; df++) o[df] *= corr;                                              \
        _Pragma("unroll")                                                                          \
        for (int kf = 0; kf < 4; kf++)                                                             \
            _Pragma("unroll")                                                                      \
            for (int j = 0; j < 2; j++) {                                                          \
                int ch = ((kf * 2 + (hg >> 1)) ^ lrs) & 7;                                         \
                *(unsigned int*)&PsW[lr * 64 + (ch << 3) + (hg & 1) * 4 + 2 * j] = pk[kf * 2 + j]; \
            }                                                                                      \
        _Pragma("unroll")                                                                          \
        for (int e = 0; e < 8; e++) {                                                              \
            int d = kch * 8 + e;                                                                   \
            int ch = ((kr >> 3) ^ e ^ kch) & 7;                                                    \
            unsigned short val = (unsigned short)(((const unsigned int*)&tv)[e >> 1] >>            \
                                                  ((e & 1) * 16));                                 \
            Vt[d * 64 + (ch << 3) + (kr & 7)] = val;                                               \
        }                                                                                          \
        __syncthreads();                                                                           \
        bf16x8 pb0 = *(const bf16x8*)&PsW[lr * 64 + ((hg ^ lrs) << 3)];                            \
        bf16x8 pb1 = *(const bf16x8*)&PsW[lr * 64 + (((4 + hg) ^ lrs) << 3)];                      \
        _Pragma("unroll")                                                                          \
        for (int df = 0; df < 4; df++) {                                                           \
            int sw = lrs ^ (df * 2);                                                               \
            bf16x8 v0 = *(const bf16x8*)&Vt[(df * 16 + lr) * 64 + ((hg ^ sw) << 3)];               \
            bf16x8 v1 = *(const bf16x8*)&Vt[(df * 16 + lr) * 64 + (((4 + hg) ^ sw) << 3)];         \
            o[df] = mfma16(v1, pb1, mfma16(v0, pb0, o[df]));                                       \
        }                                                                                          \
        __syncthreads();                                                                           \
    }

    for (int kt = 0; kt < L_ / 64; kt += 2) {
        ATT_STEP(kt, Kb0, kdst1, true);
        ATT_STEP(kt + 1, Kb1, kdst0, (kt + 2 < L_ / 64));
    }
#undef ATT_STEP

    float rs = lst;
    rs += __shfl_xor(rs, 16, 64);
    rs += __shfl_xor(rs, 32, 64);
    float inv = 1.f / rs;
    size_t obase = (size_t)(b * L_ + qi) * 1024 + hcol;
#pragma unroll
    for (int df = 0; df < 4; df++)
#pragma unroll
        for (int r = 0; r < 4; r++)
            ctx[obase + df * 16 + hg * 4 + r] = f2bf(o[df][r] * inv);
}

// ---------------- fused residual + layernorm ----------------
template <bool WBF>
__global__ __launch_bounds__(256) void resln_kernel(const float* __restrict__ ra,
                                                    const float* __restrict__ rb,
                                                    const float* __restrict__ g,
                                                    const float* __restrict__ be,
                                                    float* __restrict__ outf,
                                                    unsigned short* __restrict__ outb) {
    __shared__ float red[4];
    __shared__ float red2[4];
    int row = blockIdx.x;
    int t = threadIdx.x;
    int w = t >> 6, lane = t & 63;
    size_t base = (size_t)row * 1024 + t * 4;
    floatx4 a = *(const floatx4*)&ra[base];
    floatx4 b = *(const floatx4*)&rb[base];
    floatx4 y = a + b;
    float s = y[0] + y[1] + y[2] + y[3];
#pragma unroll
    for (int d = 1; d < 64; d <<= 1) s += __shfl_xor(s, d, 64);
    if (lane == 0) red[w] = s;
    __syncthreads();
    float mu = (red[0] + red[1] + red[2] + red[3]) * (1.f / 1024.f);
    floatx4 d4 = y - mu;
    float sq = d4[0] * d4[0] + d4[1] * d4[1] + d4[2] * d4[2] + d4[3] * d4[3];
#pragma unroll
    for (int d = 1; d < 64; d <<= 1) sq += __shfl_xor(sq, d, 64);
    if (lane == 0) red2[w] = sq;
    __syncthreads();
    float var = (red2[0] + red2[1] + red2[2] + red2[3]) * (1.f / 1024.f);
    float rstd = rsqrtf(var + 1e-5f);
    floatx4 gg = *(const floatx4*)&g[t * 4];
    floatx4 bb = *(const floatx4*)&be[t * 4];
    floatx4 outv;
#pragma unroll
    for (int i = 0; i < 4; i++) outv[i] = d4[i] * rstd * gg[i] + bb[i];
    *(floatx4*)&outf[base] = outv;
    if (WBF) {
        ushort4v ov;
        ov.x = f2bf(outv[0]); ov.y = f2bf(outv[1]); ov.z = f2bf(outv[2]); ov.w = f2bf(outv[3]);
        *(ushort4v*)&outb[base] = ov;
    }
}

extern "C" void kernel_launch(void* const* d_in, const int* in_sizes, int n_in,
                              void* d_out, int out_size, void* d_ws, size_t ws_size,
                              hipStream_t stream) {
    const float* src = (const float*)d_in[0];
    const float* Wq = (const float*)d_in[1];
    const float* Wk = (const float*)d_in[2];
    const float* Wv = (const float*)d_in[3];
    const float* bq = (const float*)d_in[4];
    const float* bk = (const float*)d_in[5];
    const float* bv = (const float*)d_in[6];
    const float* Wo = (const float*)d_in[7];
    const float* bo = (const float*)d_in[8];
    const float* rpe = (const float*)d_in[9];
    const float* W1 = (const float*)d_in[10];
    const float* b1 = (const float*)d_in[11];
    const float* W2 = (const float*)d_in[12];
    const float* b2 = (const float*)d_in[13];
    const float* ln1g = (const float*)d_in[14];
    const float* ln1b = (const float*)d_in[15];
    const float* ln2g = (const float*)d_in[16];
    const float* ln2b = (const float*)d_in[17];
    float* out = (float*)d_out;
    char* ws = (char*)d_ws;

    const size_t o_srcb = 0;                       // 8 MB   bf16 src; later reused as xb
    const size_t o_wtqkv = o_srcb + 8388608;       // 6 MB
    const size_t o_wto = o_wtqkv + 6291456;        // 2 MB
    const size_t o_wt1 = o_wto + 2097152;          // 8 MB
    const size_t o_wt2 = o_wt1 + 8388608;          // 8 MB
    const size_t o_bqkv = o_wt2 + 8388608;         // 12 KB
    const size_t o_qkv = o_bqkv + 12288;           // 24 MB  qkv bf16; later reused as attnout/ff fp32
    const size_t o_ctxb = o_qkv + 25165824;        // 8 MB
    const size_t o_x = o_ctxb + 8388608;           // 16 MB
    const size_t o_hb = o_x + 16777216;            // 32 MB

    unsigned short* srcb = (unsigned short*)(ws + o_srcb);
    unsigned short* wtqkv = (unsigned short*)(ws + o_wtqkv);
    unsigned short* wto = (unsigned short*)(ws + o_wto);
    unsigned short* wt1 = (unsigned short*)(ws + o_wt1);
    unsigned short* wt2 = (unsigned short*)(ws + o_wt2);
    float* bqkv = (float*)(ws + o_bqkv);
    unsigned short* qkvb = (unsigned short*)(ws + o_qkv);
    unsigned short* ctxb = (unsigned short*)(ws + o_ctxb);
    float* x = (float*)(ws + o_x);
    unsigned short* hb = (unsigned short*)(ws + o_hb);
    float* attnout = (float*)(ws + o_qkv);
    float* ff = (float*)(ws + o_qkv);
    unsigned short* xb = (unsigned short*)(ws + o_srcb);

    cast_bf16_kernel<<<4096, 256, 0, stream>>>(src, srcb, 1048576);
    transpose_cast_kernel<<<dim3(32, 32), 256, 0, stream>>>(Wq, wtqkv, 1024, 1024);
    transpose_cast_kernel<<<dim3(32, 32), 256, 0, stream>>>(Wk, wtqkv + 1024 * 1024, 1024, 1024);
    transpose_cast_kernel<<<dim3(32, 32), 256, 0, stream>>>(Wv, wtqkv + 2 * 1024 * 1024, 1024, 1024);
    transpose_cast_kernel<<<dim3(32, 32), 256, 0, stream>>>(Wo, wto, 1024, 1024);
    transpose_cast_kernel<<<dim3(128, 32), 256, 0, stream>>>(W1, wt1, 1024, 4096);
    transpose_cast_kernel<<<dim3(32, 128), 256, 0, stream>>>(W2, wt2, 4096, 1024);
    pack_bias_kernel<<<12, 256, 0, stream>>>(bq, bk, bv, bqkv);

    gemm_kernel<4, true, false><<<dim3(24, 32), 256, 0, stream>>>(srcb, wtqkv, bqkv, qkvb, NROW, 3072, 1024);
    attn_kernel<<<512, 512, 0, stream>>>(qkvb, rpe, ctxb);
    gemm_kernel<2, false, false><<<dim3(16, 32), 256, 0, stream>>>(ctxb, wto, bo, attnout, NROW, 1024, 1024);
    resln_kernel<true><<<4096, 256, 0, stream>>>(src, attnout, ln1g, ln1b, x, xb);
    gemm_kernel<4, true, true><<<dim3(32, 32), 256, 0, stream>>>(xb, wt1, b1, hb, NROW, 4096, 1024);
    gemm_kernel<2, false, false><<<dim3(16, 32), 256, 0, stream>>>(hb, wt2, b2, ff, NROW, 1024, 4096);
    resln_kernel<false><<<4096, 256, 0, stream>>>(x, ff, ln2g, ln2b, out, nullptr);
}